// Round 2
// baseline (972.130 us; speedup 1.0000x reference)
//
#include <hip/hip_runtime.h>

// CCN layer promotion: promotions[n,c,a,b,s] = chi[n,c,a]*chi[n,c,b]*feat[n,c,s]
// where chi[n,c,a] = (neigh[n,a] == neigh[n,c]), feat[n,c,:] = tensors[neigh[n,c],:].
// neigh rows are pre-sorted by setup, so new_parts == neigh (output 1, as float).
//
// Pure store-bandwidth problem: 983 MB promotions + 1.3 MB new_parts.
// Roofline ~156 us at 6.3 TB/s (the harness's own 0xAA fill achieves 6.2 TB/s
// at 10% occupancy / 8 VGPRs, so streaming stores alone can saturate HBM).
//
// Round-2 design: NO LDS, NO __syncthreads. All per-c data (child id + 3
// feature floats) is wave-uniform -> forced into SGPRs via readfirstlane.
// Hot loop = v_cmp / s_and / v_cndmask / global_store_dwordx4 with zero
// lgkmcnt dependencies, so stores issue back-to-back.

constexpr int NN = 20000;
constexpr int DD = 16;
constexpr int FF = 3;
constexpr int PROMO_PER_NODE = DD * DD * DD * FF;                 // 12288 floats
constexpr long long PROMO_TOTAL = (long long)NN * PROMO_PER_NODE; // 245,760,000

// block = 192 threads: 12288 floats/node = 3072 float4; 3072/192 = 16 iters.
// float4 index q = c*192 + t; since 192 % 12 == 0, t = a*12 + k with (a,k)
// per-thread constants and the loop counter IS c. Each store instruction is
// 192 lanes x 16B = 3KB contiguous (perfect 128B-line coverage).
__global__ __launch_bounds__(192) void ccn_promote_kernel(
    const float* __restrict__ tensors,
    const int* __restrict__ neigh,
    float* __restrict__ out)
{
    const int n = blockIdx.x;
    const int t = threadIdx.x;

    const int* nrow = neigh + (size_t)n * DD;

    // output 1: new_parts (== sorted neigh) as float — tiny, independent store
    if (t < DD) {
        out[(size_t)PROMO_TOTAL + (size_t)n * DD + t] = (float)nrow[t];
    }

    // per-thread constant decode: t = a*12 + k, float4 covers flat elems 4k..4k+3
    const int a  = t / 12;       // slot index 0..15
    const int k  = t - a * 12;   // float4 within the 48-float (c,a) slab
    const int e0 = 4 * k;
    const int b0 = (e0 + 0) / 3, s0 = (e0 + 0) % 3;
    const int b1 = (e0 + 1) / 3, s1 = (e0 + 1) % 3;
    const int b2 = (e0 + 2) / 3, s2 = (e0 + 2) % 3;
    const int b3 = (e0 + 3) / 3, s3 = (e0 + 3) % 3;

    // per-lane neighbor ids (divergent 4B loads, L1/L2-hot, once per block)
    const int nva  = nrow[a];
    const int nvb0 = nrow[b0];
    const int nvb1 = nrow[b1];
    const int nvb2 = nrow[b2];
    const int nvb3 = nrow[b3];

    // per-lane constant selector bools (which feature component each elem wants)
    const bool x0 = (s0 == 0), x1 = (s0 == 1);
    const bool y0 = (s1 == 0), y1 = (s1 == 1);
    const bool z0 = (s2 == 0), z1 = (s2 == 1);
    const bool w0 = (s3 == 0), w1 = (s3 == 1);

    // wave-uniform child ids + gathered features, forced scalar (SGPRs)
    int   mc[DD];
    float g0[DD], g1[DD], g2[DD];
#pragma unroll
    for (int c = 0; c < DD; ++c) {
        mc[c] = __builtin_amdgcn_readfirstlane(nrow[c]);
    }
#pragma unroll
    for (int c = 0; c < DD; ++c) {
        const float* src = tensors + (size_t)mc[c] * FF;  // uniform address
        g0[c] = src[0];
        g1[c] = src[1];
        g2[c] = src[2];
    }

    float4* outv = reinterpret_cast<float4*>(out + (size_t)n * PROMO_PER_NODE) + t;

#pragma unroll
    for (int c = 0; c < DD; ++c) {
        const int m = mc[c];
        // select this lane's feature components from wave-uniform scalars
        const float fx = x0 ? g0[c] : (x1 ? g1[c] : g2[c]);
        const float fy = y0 ? g0[c] : (y1 ? g1[c] : g2[c]);
        const float fz = z0 ? g0[c] : (z1 ? g1[c] : g2[c]);
        const float fw = w0 ? g0[c] : (w1 ? g1[c] : g2[c]);
        const bool ca = (nva == m);
        float4 v;
        v.x = (ca && (nvb0 == m)) ? fx : 0.0f;
        v.y = (ca && (nvb1 == m)) ? fy : 0.0f;
        v.z = (ca && (nvb2 == m)) ? fz : 0.0f;
        v.w = (ca && (nvb3 == m)) ? fw : 0.0f;
        outv[c * 192] = v;   // 192 lanes x 16B = 3KB contiguous per instruction
    }
}

extern "C" void kernel_launch(void* const* d_in, const int* in_sizes, int n_in,
                              void* d_out, int out_size, void* d_ws, size_t ws_size,
                              hipStream_t stream) {
    const float* tensors = (const float*)d_in[0];  // [N, F] float32
    const int*   neigh   = (const int*)d_in[1];    // [N, D] int32 (sorted rows)
    float*       out     = (float*)d_out;          // promotions flat + new_parts flat

    ccn_promote_kernel<<<NN, 192, 0, stream>>>(tensors, neigh, out);
}